// Round 13
// baseline (491.287 us; speedup 1.0000x reference)
//
#include <hip/hip_runtime.h>
#include <hip/hip_bf16.h>

// Top2Router: T=16384, D=4096, E=64.
// logits = x @ W^T + b; probs = softmax(logits); top2; gating = scatter(softmax(top2_probs))
//
// R7 design (sixth resubmit; never benched -- infra failures):
//  - gemm: 256 blocks (T/256 x KSPLIT=4), 1 block/CU, 4 waves x 64 tokens.
//    A (x) streamed per-wave via global_load_lds dbuf + counted vmcnt(8) -- NO barrier in k-loop.
//    B (W hi/lo bf16) staged per 256-k sub-slice (64 KiB LDS), XOR-swizzled both sides.
//    split-bf16 MFMA (hi*hi + lo*hi + hi*lo). Deterministic partials (no atomics).
//  - finalize: wave-per-token: sum partials + b, softmax/top2/scatter; gap<TAU rows flagged
//  - fallback: exact fp32 recompute of flagged rows (flip-proof)

typedef float  f32x4 __attribute__((ext_vector_type(4)));
typedef short  s16x8 __attribute__((ext_vector_type(8)));   // 8 bf16 = 4 VGPRs (MFMA A/B frag)
typedef short  s16x4 __attribute__((ext_vector_type(4)));
typedef unsigned int u32;

#define T_TOK   16384
#define D_DIM   4096
#define E_EXP   64
#define KSPLIT  4
#define KSLICE  (D_DIM / KSPLIT)   // 1024 per block
#define SUBK    256                // B sub-slice staged in LDS
#define KCHUNK  32                 // A chunk (one MFMA K-step)
#define TAU     0.004f
#define WS_NEED (17 * 1024 * 1024 + 4 + 4 * T_TOK)

// ---------------- helpers ----------------
__device__ __forceinline__ unsigned short f2bf_rn(float f) {
    unsigned u = __builtin_bit_cast(unsigned, f);
    unsigned r = u + 0x7fffu + ((u >> 16) & 1u);
    return (unsigned short)(r >> 16);
}

__device__ __forceinline__ void gl16(const void* g, void* l) {
    // async global->LDS, 16B/lane; HW dest = wave-uniform lds addr + lane*16 (m104)
    __builtin_amdgcn_global_load_lds((const __attribute__((address_space(1))) u32*)g,
                                     (__attribute__((address_space(3))) u32*)l, 16, 0, 0);
}

// ---------------- kernel 1: one-time W -> (W_hi, W_lo) bf16 split ----------------
__global__ __launch_bounds__(256)
void convw_kernel(const float* __restrict__ W, short* __restrict__ Whi, short* __restrict__ Wlo) {
    const int i = (blockIdx.x * 256 + threadIdx.x) * 4;
    f32x4 v = *(const f32x4*)(W + i);
    s16x4 h, l;
#pragma unroll
    for (int j = 0; j < 4; ++j) {
        unsigned short hb = f2bf_rn(v[j]);
        h[j] = (short)hb;
        float hf = __builtin_bit_cast(float, (unsigned)hb << 16);
        l[j] = (short)f2bf_rn(v[j] - hf);
    }
    *(s16x4*)(Whi + i) = h;
    *(s16x4*)(Wlo + i) = l;
}

// ---------------- kernel 2: logits GEMM -------------------------------------------------
// grid = (T/256, KSPLIT). LDS: B [2][64 e][512 B] = 64 KiB (per sub-slice),
// A [4 wave][2 buf][64 tok][128 B] = 64 KiB (per-wave private dbuf). Total 128 KiB -> 1 blk/CU.
// Swizzle (both A and B rows): byte col ^= ((row&7)<<4)  (stage src pre-swizzled, read swizzled).
// A frag: row=lane&15, k=(lane>>4)*8+j ; B frag: col=n*16+(lane&15) ; C/D: col=lane&15,
// row=(lane>>4)*4+reg (m89; validated by R6 pass).
__global__ __launch_bounds__(256, 1)
void gemm_logits(const float* __restrict__ x, const short* __restrict__ Whi,
                 const short* __restrict__ Wlo, float* __restrict__ partial) {
    __shared__ __align__(16) char Blds[2][64 * 512];        // 64 KiB  [hi/lo][e*512B]
    __shared__ __align__(16) char Alds[4][2][64 * 128];     // 64 KiB  [wave][buf][tok*128B]
    const int lane = threadIdx.x & 63;
    const int wid  = threadIdx.x >> 6;
    const int r16  = lane & 15;
    const int q16  = lane >> 4;
    const int wtb  = blockIdx.x * 256 + wid * 64;           // wave token base
    const int kbase = blockIdx.y * KSLICE;

    f32x4 acc[4][4];
#pragma unroll
    for (int m = 0; m < 4; ++m)
#pragma unroll
        for (int n = 0; n < 4; ++n) acc[m][n] = (f32x4){0.f, 0.f, 0.f, 0.f};

    // A chunk stage: 8 KiB (64 tok x 32 k fp32), wave-private, inverse-swizzled source
#define ASTAGE(buf_, kglob_)                                                         \
    { _Pragma("unroll")                                                              \
      for (int r = 0; r < 8; ++r) {                                                  \
          const int o   = r * 1024 + lane * 16;                                      \
          const int tok = o >> 7;                                                    \
          const int scol = (o & 127) ^ ((tok & 7) << 4);                             \
          gl16((const char*)(x + (long)(wtb + tok) * D_DIM + (kglob_)) + scol,       \
               &Alds[wid][buf_][0] + r * 1024);                                      \
      } }

    // B sub-slice stage: 64 KiB cooperative (hi 32K + lo 32K), inverse-swizzled source
#define BSTAGE(kglob_)                                                               \
    { _Pragma("unroll")                                                              \
      for (int h = 0; h < 2; ++h) {                                                  \
          const short* Wsrc = h ? Wlo : Whi;                                         \
          _Pragma("unroll")                                                          \
          for (int r = 0; r < 8; ++r) {                                              \
              const int o = wid * 8192 + r * 1024 + lane * 16;                       \
              const int e = o >> 9;                                                  \
              const int scol = (o & 511) ^ ((e & 7) << 4);                           \
              gl16((const char*)(Wsrc + (long)e * D_DIM + (kglob_)) + scol,          \
                   &Blds[h][0] + wid * 8192 + r * 1024);                             \
          } } }

#pragma unroll 1
    for (int ss = 0; ss < KSLICE / SUBK; ++ss) {
        const int kss = kbase + ss * SUBK;
        __syncthreads();                       // all waves done reading previous B
        BSTAGE(kss);
        ASTAGE(0, kss);                        // chunk 0 of this sub-slice
        __syncthreads();                       // vmcnt(0) drain: B + A0 landed

#pragma unroll
        for (int c = 0; c < SUBK / KCHUNK; ++c) {
            const int buf = c & 1;
            if (c < SUBK / KCHUNK - 1) {
                ASTAGE(buf ^ 1, kss + (c + 1) * KCHUNK);
                asm volatile("s_waitcnt vmcnt(8)" ::: "memory");   // chunk c landed; 8 in flight
            } else {
                asm volatile("s_waitcnt vmcnt(0)" ::: "memory");
            }
            __builtin_amdgcn_sched_barrier(0);

            // A: LDS -> regs, split hi/lo
            s16x8 ahi[4], alo[4];
#pragma unroll
            for (int m = 0; m < 4; ++m) {
                const int tok = m * 16 + r16;
                const char* ab = &Alds[wid][buf][0] + tok * 128;
                const int sw = (tok & 7) << 4;
                f32x4 a0 = *(const f32x4*)(ab + ((q16 * 32) ^ sw));
                f32x4 a1 = *(const f32x4*)(ab + ((q16 * 32 + 16) ^ sw));
#pragma unroll
                for (int j = 0; j < 8; ++j) {
                    float f = (j < 4) ? a0[j] : a1[j - 4];
                    u32 u = __builtin_bit_cast(u32, f);
                    float hf = __builtin_bit_cast(float, u & 0xffff0000u);
                    ahi[m][j] = (short)(u >> 16);
                    alo[m][j] = (short)(__builtin_bit_cast(u32, f - hf) >> 16);
                }
            }
            // B: LDS -> regs, 3 MFMAs per (m,n)
            const int bcol = c * 64 + q16 * 16;
#pragma unroll
            for (int n = 0; n < 4; ++n) {
                const int e = n * 16 + r16;
                const int off = e * 512 + (bcol ^ ((e & 7) << 4));
                s16x8 bhi = *(const s16x8*)(&Blds[0][0] + off);
                s16x8 blo = *(const s16x8*)(&Blds[1][0] + off);
#pragma unroll
                for (int m = 0; m < 4; ++m) {
                    acc[m][n] = __builtin_amdgcn_mfma_f32_16x16x32_bf16(ahi[m], bhi, acc[m][n], 0, 0, 0);
                    acc[m][n] = __builtin_amdgcn_mfma_f32_16x16x32_bf16(alo[m], bhi, acc[m][n], 0, 0, 0);
                    acc[m][n] = __builtin_amdgcn_mfma_f32_16x16x32_bf16(ahi[m], blo, acc[m][n], 0, 0, 0);
                }
            }
        }
    }

    float* Pk = partial + (long)blockIdx.y * T_TOK * E_EXP;
#pragma unroll
    for (int m = 0; m < 4; ++m) {
        const long rb = (long)(wtb + m * 16 + q16 * 4);
#pragma unroll
        for (int n = 0; n < 4; ++n)
#pragma unroll
            for (int j = 0; j < 4; ++j)
                Pk[(rb + j) * E_EXP + n * 16 + r16] = acc[m][n][j];
    }
#undef ASTAGE
#undef BSTAGE
}

// ---------------- per-wave gating: softmax + top2 + scatter; returns (2nd - 3rd) gap ----
__device__ __forceinline__ void argmax64(float& v, int& i) {
#pragma unroll
    for (int s = 32; s > 0; s >>= 1) {
        float ov = __shfl_xor(v, s);
        int   oi = __shfl_xor(i, s);
        if (ov > v || (ov == v && oi < i)) { v = ov; i = oi; }   // tie-break: lower index (top_k)
    }
}

__device__ __forceinline__ float wave_gate_write(float l, int lane, float* __restrict__ outrow) {
    float v1 = l; int i1 = lane; argmax64(v1, i1);
    float v2 = (lane == i1) ? -INFINITY : l; int i2 = lane; argmax64(v2, i2);
    float v3 = (lane == i1 || lane == i2) ? -INFINITY : l; int i3 = lane; argmax64(v3, i3);
    (void)i3;

    float ex = __expf(l - v1);
    float Z = ex;
#pragma unroll
    for (int s = 32; s > 0; s >>= 1) Z += __shfl_xor(Z, s);

    float p1 = 1.0f / Z;                   // top-1 probability
    float p2 = __expf(v2 - v1) / Z;        // top-2 probability
    float g1 = 1.0f / (1.0f + __expf(p2 - p1));   // softmax over [p1,p2] (probs, per reference)
    float g2 = 1.0f / (1.0f + __expf(p1 - p2));

    outrow[lane] = (lane == i1) ? g1 : (lane == i2) ? g2 : 0.0f;
    return v2 - v3;
}

// ---------------- kernel 3: finalize (partials -> gating) + flag risky rows -------------
__global__ __launch_bounds__(256)
void finalize_router(const float* __restrict__ part, const float* __restrict__ b,
                     float* __restrict__ out, int* __restrict__ flagc,
                     int* __restrict__ flaglist) {
    const int lane = threadIdx.x & 63;
    const int t = blockIdx.x * 4 + (threadIdx.x >> 6);
    float l = b[lane];
#pragma unroll
    for (int ks = 0; ks < KSPLIT; ++ks)
        l += part[(long)ks * T_TOK * E_EXP + (long)t * E_EXP + lane];
    float gap = wave_gate_write(l, lane, out + (long)t * E_EXP);
    if (gap < TAU && lane == 0) {
        int pos = atomicAdd(flagc, 1);
        flaglist[pos] = t;
    }
}

// ---------------- exact fp32 row compute (shared by fallback + no-ws path) --------------
__device__ __forceinline__ void exact_row(const float* __restrict__ x, const float* __restrict__ W,
                                          const float* __restrict__ b, float* __restrict__ out,
                                          int t, int lane, int w, float (*lds)[64]) {
    const float* xr = x + (long)t * D_DIM + w * 1024;
    const float* wr = W + (long)lane * D_DIM + w * 1024;
    float acc = 0.f;
    for (int k = 0; k < 1024; k += 4) {
        f32x4 xv = *(const f32x4*)(xr + k);
        f32x4 wv = *(const f32x4*)(wr + k);
        acc += xv[0]*wv[0] + xv[1]*wv[1] + xv[2]*wv[2] + xv[3]*wv[3];
    }
    lds[w][lane] = acc;
    __syncthreads();
    if (w == 0) {
        float l = lds[0][lane] + lds[1][lane] + lds[2][lane] + lds[3][lane] + b[lane];
        wave_gate_write(l, lane, out + (long)t * E_EXP);
    }
    __syncthreads();
}

// ---------------- kernel 4: exact fp32 recompute for flagged rows -----------------------
__global__ __launch_bounds__(256)
void fallback_exact(const float* __restrict__ x, const float* __restrict__ W,
                    const float* __restrict__ b, float* __restrict__ out,
                    const int* __restrict__ flags) {
    const int count = flags[0];
    const int lane = threadIdx.x & 63;
    const int w = threadIdx.x >> 6;
    __shared__ float lds[4][64];
    for (int fi = blockIdx.x; fi < count; fi += gridDim.x)
        exact_row(x, W, b, out, flags[1 + fi], lane, w, lds);
}

// ---------------- no-workspace safety net: exact fp32 for ALL rows ----------------------
__global__ __launch_bounds__(256)
void exact_all(const float* __restrict__ x, const float* __restrict__ W,
               const float* __restrict__ b, float* __restrict__ out) {
    const int lane = threadIdx.x & 63;
    const int w = threadIdx.x >> 6;
    __shared__ float lds[4][64];
    for (int t = blockIdx.x; t < T_TOK; t += gridDim.x)
        exact_row(x, W, b, out, t, lane, w, lds);
}

// ---------------- launch ----------------------------------------------------------------
extern "C" void kernel_launch(void* const* d_in, const int* in_sizes, int n_in,
                              void* d_out, int out_size, void* d_ws, size_t ws_size,
                              hipStream_t stream) {
    const float* x = (const float*)d_in[0];
    const float* W = (const float*)d_in[1];
    const float* b = (const float*)d_in[2];
    float* out = (float*)d_out;

    if (ws_size < (size_t)WS_NEED) {           // constant per-session -> graph-safe
        exact_all<<<2048, 256, 0, stream>>>(x, W, b, out);
        return;
    }

    char* ws = (char*)d_ws;
    short* Whi    = (short*)ws;                               // 512 KiB
    short* Wlo    = (short*)(ws + 512 * 1024);                // 512 KiB
    float* partial = (float*)(ws + 1024 * 1024);              // 16 MiB (KSPLIT x T x E fp32)
    int* flagc    = (int*)(ws + 17 * 1024 * 1024);            // 4 B
    int* flaglist = flagc + 1;                                // up to 16384 ints

    hipMemsetAsync(flagc, 0, sizeof(int), stream);

    convw_kernel<<<256, 256, 0, stream>>>(W, Whi, Wlo);
    gemm_logits<<<dim3(T_TOK / 256, KSPLIT), 256, 0, stream>>>(x, Whi, Wlo, partial);
    finalize_router<<<T_TOK / 4, 256, 0, stream>>>(partial, b, out, flagc, flaglist);
    fallback_exact<<<1024, 256, 0, stream>>>(x, W, b, out, flagc);
}